// Round 1
// baseline (8285.349 us; speedup 1.0000x reference)
//
#include <hip/hip_runtime.h>

#define S_LEN 2048
#define NH 16
#define DIM 128
#define KSZ 32
#define STRD 16
#define SSZ 64
#define NSELB 32
#define NCMP 127
#define TOPN 16
#define WINSZ 512
#define NEGF (-1e30f)
#define SCALE 0.088388347648318447f

// ---------- kernel 1: mean-pool K/V into compressed blocks ----------
__global__ __launch_bounds__(128) void nsa_compress(
    const float* __restrict__ k, const float* __restrict__ v,
    float* __restrict__ cmpk, float* __restrict__ cmpv)
{
  const int c = blockIdx.x % NCMP;
  const int h = blockIdx.x / NCMP;
  const int d = threadIdx.x;
  const int base = ((c * STRD) * NH + h) * DIM + d;
  float sk = 0.f, sv = 0.f;
#pragma unroll
  for (int i = 0; i < KSZ; ++i) {
    sk += k[base + i * NH * DIM];
    sv += v[base + i * NH * DIM];
  }
  cmpk[(h * NCMP + c) * DIM + d] = sk * (1.0f / KSZ);
  cmpv[(h * NCMP + c) * DIM + d] = sv * (1.0f / KSZ);
}

__device__ __forceinline__ float wave_max(float x) {
  for (int off = 32; off; off >>= 1) x = fmaxf(x, __shfl_xor(x, off));
  return x;
}
__device__ __forceinline__ float wave_sum(float x) {
  for (int off = 32; off; off >>= 1) x += __shfl_xor(x, off);
  return x;
}

// ---------- kernel 2: one block per (t, h) ----------
__global__ __launch_bounds__(256) void nsa_main(
    const float* __restrict__ q, const float* __restrict__ k,
    const float* __restrict__ v, const float* __restrict__ wg,
    const float* __restrict__ bg, const float* __restrict__ cmpk,
    const float* __restrict__ cmpv, float* __restrict__ out)
{
  __shared__ __align__(16) float q_s[DIM];
  __shared__ float sc_cmp[NCMP + 1];
  __shared__ float p_cmp[NCMP + 1];
  __shared__ float sc_blk[NSELB];
  __shared__ int blist[TOPN];
  __shared__ int nsel_cnt;
  __shared__ float gates[4];
  __shared__ float o_win[DIM];
  __shared__ float skey[1024 + 520];   // selected scores then window scores

  const int bid = blockIdx.x;
  const int h = bid >> 11;           // bid / S_LEN
  const int t = bid & (S_LEN - 1);
  const int tid = threadIdx.x;
  const int lane = tid & 63;
  const int wave = tid >> 6;

  if (tid < DIM) q_s[tid] = q[(t * NH + h) * DIM + tid];
  __syncthreads();

  // number of compressed blocks fully in the past: c*16+31 <= t
  const int nvalid = (t >= KSZ - 1) ? ((t - (KSZ - 1)) / STRD + 1) : 0;

  // ---- phase 1: compressed scores (tid<127) + gates (tid 200..202) ----
  if (tid < NCMP) {
    float s = NEGF;
    if (tid < nvalid) {
      const float* kr = cmpk + (h * NCMP + tid) * DIM;
      float acc = 0.f;
#pragma unroll
      for (int d4 = 0; d4 < DIM; d4 += 4) {
        const float4 kv = *(const float4*)(kr + d4);
        const float4 qv = *(const float4*)(q_s + d4);
        acc += qv.x * kv.x + qv.y * kv.y + qv.z * kv.z + qv.w * kv.w;
      }
      s = acc * SCALE;
    }
    sc_cmp[tid] = s;
  } else if (tid >= 200 && tid < 203) {
    const int g = tid - 200;
    float acc = bg[g];
    for (int d = 0; d < DIM; ++d) acc += q_s[d] * wg[d * 3 + g];
    gates[g] = 1.0f / (1.0f + __expf(-acc));
  }
  __syncthreads();

  // ---- phase 2: softmax over compressed scores (wave 0) ----
  if (wave == 0) {
    const float s0 = (lane < nvalid) ? sc_cmp[lane] : NEGF;
    const float s1 = (lane + 64 < nvalid) ? sc_cmp[lane + 64] : NEGF;
    const float m = wave_max(fmaxf(s0, s1));
    const float e0 = (lane < nvalid) ? __expf(s0 - m) : 0.f;
    const float e1 = (lane + 64 < nvalid) ? __expf(s1 - m) : 0.f;
    const float ssum = wave_sum(e0 + e1);
    const float inv = (ssum > 0.f) ? (1.0f / ssum) : 0.f;
    p_cmp[lane] = e0 * inv;
    p_cmp[lane + 64] = e1 * inv;
  }
  __syncthreads();

  // ---- phase 3: cmp_o (tid<128) and selection scores (tid 128..159) ----
  float ocmp = 0.f;
  if (tid < DIM) {
    for (int c = 0; c < nvalid; ++c)
      ocmp += p_cmp[c] * cmpv[(h * NCMP + c) * DIM + tid];
  } else if (tid < DIM + NSELB) {
    const int j = tid - DIM;
    // overlap range: c in [max(0,4j-1), min(126,4j+3)]
    const int clo = (4 * j - 1 > 0) ? 4 * j - 1 : 0;
    const int chi = (4 * j + 3 < NCMP - 1) ? 4 * j + 3 : NCMP - 1;
    float ps = 0.f;
    for (int c = clo; c <= chi; ++c) ps += p_cmp[c];
    float sc = (j * SSZ <= t) ? ps : -1.0f;
    if (j == (t >> 6)) sc += 1e6f;   // force current block
    sc_blk[j] = sc;
  }
  __syncthreads();

  // ---- phase 4: top-16 selection set (wave 0, deterministic) ----
  if (wave == 0) {
    bool selp = false;
    if (lane < NSELB) {
      const float my = sc_blk[lane];
      int rank = 0;
      for (int j = 0; j < NSELB; ++j) {
        const float o = sc_blk[j];
        rank += (o > my) || (o == my && j < lane);
      }
      // disallowed blocks picked as filler are fully causal-masked; drop them
      selp = (rank < TOPN) && (lane * SSZ <= t);
    }
    const unsigned long long bal = __ballot(selp);
    if (selp) blist[__popcll(bal & ((1ull << lane) - 1ull))] = lane;
    if (lane == 0) nsel_cnt = (int)__popcll(bal);
  }
  __syncthreads();

  const int nksel = nsel_cnt * SSZ;
  const int w0 = (t >= WINSZ) ? t - WINSZ : 0;
  const int nkwin = t - w0 + 1;
  const int ntot = nksel + nkwin;

  // ---- phase 5: QK for selected + window keys ----
  for (int idx = tid; idx < ntot; idx += 256) {
    int tp;
    bool valid = true;
    if (idx < nksel) {
      tp = blist[idx >> 6] * SSZ + (idx & 63);
      valid = (tp <= t);
    } else {
      tp = w0 + (idx - nksel);
    }
    float s = NEGF;
    if (valid) {
      const float* kr = k + (tp * NH + h) * DIM;
      float acc = 0.f;
#pragma unroll
      for (int d4 = 0; d4 < DIM; d4 += 4) {
        const float4 kv = *(const float4*)(kr + d4);
        const float4 qv = *(const float4*)(q_s + d4);
        acc += qv.x * kv.x + qv.y * kv.y + qv.z * kv.z + qv.w * kv.w;
      }
      s = acc * SCALE;
    }
    skey[idx] = s;
  }
  __syncthreads();

  // ---- phase 6: softmax; wave0 -> selected segment, wave1 -> window ----
  if (wave == 0) {
    float m = NEGF;
    for (int i = lane; i < nksel; i += 64) m = fmaxf(m, skey[i]);
    m = wave_max(m);
    float ssum = 0.f;
    for (int i = lane; i < nksel; i += 64) {
      const float e = __expf(skey[i] - m);
      skey[i] = e;
      ssum += e;
    }
    ssum = wave_sum(ssum);
    const float inv = 1.0f / ssum;
    for (int i = lane; i < nksel; i += 64) skey[i] *= inv;
  } else if (wave == 1) {
    float m = NEGF;
    for (int i = nksel + lane; i < ntot; i += 64) m = fmaxf(m, skey[i]);
    m = wave_max(m);
    float ssum = 0.f;
    for (int i = nksel + lane; i < ntot; i += 64) {
      const float e = __expf(skey[i] - m);
      skey[i] = e;
      ssum += e;
    }
    ssum = wave_sum(ssum);
    const float inv = 1.0f / ssum;
    for (int i = nksel + lane; i < ntot; i += 64) skey[i] *= inv;
  }
  __syncthreads();

  // ---- phase 7: PV — tid<128: selected branch; tid>=128: window branch ----
  float osel = 0.f;
  if (tid < DIM) {
    const int d = tid;
    for (int idx = 0; idx < nksel; ++idx) {
      const float p = skey[idx];               // wave-uniform broadcast
      if (p != 0.f) {
        const int tp = blist[idx >> 6] * SSZ + (idx & 63);
        osel += p * v[(tp * NH + h) * DIM + d];
      }
    }
  } else {
    const int d = tid - DIM;
    float acc = 0.f;
    for (int idx = nksel; idx < ntot; ++idx)
      acc += skey[idx] * v[((w0 + idx - nksel) * NH + h) * DIM + d];
    o_win[d] = acc;
  }
  __syncthreads();

  // ---- phase 8: gated combine ----
  if (tid < DIM) {
    out[(t * NH + h) * DIM + tid] =
        ocmp * gates[0] + osel * gates[1] + o_win[tid] * gates[2];
  }
}

extern "C" void kernel_launch(void* const* d_in, const int* in_sizes, int n_in,
                              void* d_out, int out_size, void* d_ws, size_t ws_size,
                              hipStream_t stream) {
  const float* q  = (const float*)d_in[0];
  const float* k  = (const float*)d_in[1];
  const float* v  = (const float*)d_in[2];
  const float* wg = (const float*)d_in[3];
  const float* bg = (const float*)d_in[4];
  float* out = (float*)d_out;

  float* cmpk = (float*)d_ws;                 // [H][C][D] = 1,040,384 B
  float* cmpv = cmpk + NH * NCMP * DIM;       // same size

  nsa_compress<<<NCMP * NH, 128, 0, stream>>>(k, v, cmpk, cmpv);
  nsa_main<<<NH * S_LEN, 256, 0, stream>>>(q, k, v, wg, bg, cmpk, cmpv, out);
}

// Round 2
// 7008.435 us; speedup vs baseline: 1.1822x; 1.1822x over previous
//
#include <hip/hip_runtime.h>

#define S_LEN 2048
#define NH 16
#define DIM 128
#define KSZ 32
#define STRD 16
#define SSZ 64
#define NSELB 32
#define NCMP 127
#define TOPN 16
#define WINSZ 512
#define NEGF (-1e30f)
#define SCALE 0.088388347648318447f
#define NT 512
#define NW 8

// ---------- kernel 1: mean-pool K/V into compressed blocks ----------
__global__ __launch_bounds__(128) void nsa_compress(
    const float* __restrict__ k, const float* __restrict__ v,
    float* __restrict__ cmpk, float* __restrict__ cmpv)
{
  const int c = blockIdx.x % NCMP;
  const int h = blockIdx.x / NCMP;
  const int d = threadIdx.x;
  const int base = ((c * STRD) * NH + h) * DIM + d;
  float sk = 0.f, sv = 0.f;
#pragma unroll
  for (int i = 0; i < KSZ; ++i) {
    sk += k[base + i * NH * DIM];
    sv += v[base + i * NH * DIM];
  }
  cmpk[(h * NCMP + c) * DIM + d] = sk * (1.0f / KSZ);
  cmpv[(h * NCMP + c) * DIM + d] = sv * (1.0f / KSZ);
}

__device__ __forceinline__ float wave_max(float x) {
  for (int off = 32; off; off >>= 1) x = fmaxf(x, __shfl_xor(x, off));
  return x;
}
__device__ __forceinline__ float wave_sum(float x) {
  for (int off = 32; off; off >>= 1) x += __shfl_xor(x, off);
  return x;
}

// ---------- kernel 2: one block (8 waves) per (t, h) ----------
__global__ __launch_bounds__(NT) void nsa_main(
    const float* __restrict__ q, const float* __restrict__ k,
    const float* __restrict__ v, const float* __restrict__ wg,
    const float* __restrict__ bg, const float* __restrict__ cmpk,
    const float* __restrict__ cmpv, float* __restrict__ out)
{
  __shared__ __align__(16) float q_s[DIM];
  __shared__ float sc_cmp[DIM];
  __shared__ float p_cmp[DIM];
  __shared__ float sc_blk[NSELB];
  __shared__ int blist[TOPN];
  __shared__ int nsel_cnt;
  __shared__ float gates[4];
  __shared__ float skey[1024 + 520];
  __shared__ float part_cmp[NW][DIM];
  __shared__ float part_sel[NW][DIM];
  __shared__ float part_win[NW][DIM];

  const int bid = blockIdx.x;
  const int h = bid >> 11;
  const int t = bid & (S_LEN - 1);
  const int tid = threadIdx.x;
  const int lane = tid & 63;
  const int wave = tid >> 6;

  if (tid < DIM) q_s[tid] = q[(t * NH + h) * DIM + tid];
  __syncthreads();

  const int nvalid = (t >= KSZ - 1) ? ((t - (KSZ - 1)) / STRD + 1) : 0;

  // ---- phase 1: compressed scores (tid<127) + gates (wave 7) ----
  if (tid < NCMP) {
    float s = NEGF;
    if (tid < nvalid) {
      const float* kr = cmpk + (h * NCMP + tid) * DIM;
      float a0 = 0.f, a1 = 0.f, a2 = 0.f, a3 = 0.f;
#pragma unroll
      for (int d4 = 0; d4 < DIM; d4 += 16) {
        float4 kv, qv;
        kv = *(const float4*)(kr + d4);      qv = *(const float4*)(q_s + d4);
        a0 += qv.x*kv.x + qv.y*kv.y + qv.z*kv.z + qv.w*kv.w;
        kv = *(const float4*)(kr + d4 + 4);  qv = *(const float4*)(q_s + d4 + 4);
        a1 += qv.x*kv.x + qv.y*kv.y + qv.z*kv.z + qv.w*kv.w;
        kv = *(const float4*)(kr + d4 + 8);  qv = *(const float4*)(q_s + d4 + 8);
        a2 += qv.x*kv.x + qv.y*kv.y + qv.z*kv.z + qv.w*kv.w;
        kv = *(const float4*)(kr + d4 + 12); qv = *(const float4*)(q_s + d4 + 12);
        a3 += qv.x*kv.x + qv.y*kv.y + qv.z*kv.z + qv.w*kv.w;
      }
      s = ((a0 + a1) + (a2 + a3)) * SCALE;
    }
    sc_cmp[tid] = s;
  } else if (tid == NCMP) {
    sc_cmp[NCMP] = NEGF;
  }
  if (wave == 7) {
#pragma unroll
    for (int g = 0; g < 3; ++g) {
      float p = q_s[lane] * wg[lane * 3 + g] +
                q_s[lane + 64] * wg[(lane + 64) * 3 + g];
      p = wave_sum(p);
      if (lane == 0) gates[g] = 1.0f / (1.0f + __expf(-(p + bg[g])));
    }
  }
  __syncthreads();

  // ---- phase 2: softmax over compressed scores (wave 0) ----
  if (wave == 0) {
    const float s0 = (lane < nvalid) ? sc_cmp[lane] : NEGF;
    const float s1 = (lane + 64 < nvalid) ? sc_cmp[lane + 64] : NEGF;
    const float m = wave_max(fmaxf(s0, s1));
    const float e0 = (lane < nvalid) ? __expf(s0 - m) : 0.f;
    const float e1 = (lane + 64 < nvalid) ? __expf(s1 - m) : 0.f;
    const float ssum = wave_sum(e0 + e1);
    const float inv = (ssum > 0.f) ? (1.0f / ssum) : 0.f;
    p_cmp[lane] = e0 * inv;
    p_cmp[lane + 64] = e1 * inv;
  }
  __syncthreads();

  // ---- phase 3: cmp_o partials (all waves) + selection scores (tid<32) ----
  {
    float2 ac = {0.f, 0.f};
    const float* vb = cmpv + h * NCMP * DIM + 2 * lane;
    for (int c = wave; c < nvalid; c += NW) {
      const float p = p_cmp[c];
      const float2 r = *(const float2*)(vb + c * DIM);
      ac.x += p * r.x; ac.y += p * r.y;
    }
    part_cmp[wave][2 * lane] = ac.x;
    part_cmp[wave][2 * lane + 1] = ac.y;
  }
  if (tid < NSELB) {
    const int j = tid;
    const int clo = (4 * j - 1 > 0) ? 4 * j - 1 : 0;
    const int chi = (4 * j + 3 < NCMP - 1) ? 4 * j + 3 : NCMP - 1;
    float ps = 0.f;
    for (int c = clo; c <= chi; ++c) ps += p_cmp[c];
    float sc = (j * SSZ <= t) ? ps : -1.0f;
    if (j == (t >> 6)) sc += 1e6f;
    sc_blk[j] = sc;
  }
  __syncthreads();

  // ---- phase 4: top-16 selection set (wave 0, deterministic) ----
  if (wave == 0) {
    bool selp = false;
    if (lane < NSELB) {
      const float my = sc_blk[lane];
      int rank = 0;
#pragma unroll
      for (int j = 0; j < NSELB; ++j) {
        const float o = sc_blk[j];
        rank += (o > my) || (o == my && j < lane);
      }
      selp = (rank < TOPN) && (lane * SSZ <= t);
    }
    const unsigned long long bal = __ballot(selp);
    if (selp) blist[__popcll(bal & ((1ull << lane) - 1ull))] = lane;
    if (lane == 0) nsel_cnt = (int)__popcll(bal);
  }
  __syncthreads();

  const int nksel = nsel_cnt * SSZ;
  const int w0 = (t >= WINSZ) ? t - WINSZ : 0;
  const int nkwin = t - w0 + 1;
  const int ntot = nksel + nkwin;

  // ---- phase 5: QK for selected + window keys (all 512 threads) ----
  for (int idx = tid; idx < ntot; idx += NT) {
    int tp;
    bool valid = true;
    if (idx < nksel) {
      tp = blist[idx >> 6] * SSZ + (idx & 63);
      valid = (tp <= t);
    } else {
      tp = w0 + (idx - nksel);
    }
    float s = NEGF;
    if (valid) {
      const float* kr = k + (tp * NH + h) * DIM;
      float a0 = 0.f, a1 = 0.f, a2 = 0.f, a3 = 0.f;
#pragma unroll
      for (int d4 = 0; d4 < DIM; d4 += 16) {
        float4 kv, qv;
        kv = *(const float4*)(kr + d4);      qv = *(const float4*)(q_s + d4);
        a0 += qv.x*kv.x + qv.y*kv.y + qv.z*kv.z + qv.w*kv.w;
        kv = *(const float4*)(kr + d4 + 4);  qv = *(const float4*)(q_s + d4 + 4);
        a1 += qv.x*kv.x + qv.y*kv.y + qv.z*kv.z + qv.w*kv.w;
        kv = *(const float4*)(kr + d4 + 8);  qv = *(const float4*)(q_s + d4 + 8);
        a2 += qv.x*kv.x + qv.y*kv.y + qv.z*kv.z + qv.w*kv.w;
        kv = *(const float4*)(kr + d4 + 12); qv = *(const float4*)(q_s + d4 + 12);
        a3 += qv.x*kv.x + qv.y*kv.y + qv.z*kv.z + qv.w*kv.w;
      }
      s = ((a0 + a1) + (a2 + a3)) * SCALE;
    }
    skey[idx] = s;
  }
  __syncthreads();

  // ---- phase 6: softmax; wave0 -> selected segment, wave1 -> window ----
  if (wave == 0) {
    float m = NEGF;
    for (int i = lane; i < nksel; i += 64) m = fmaxf(m, skey[i]);
    m = wave_max(m);
    float ssum = 0.f;
    for (int i = lane; i < nksel; i += 64) {
      const float e = __expf(skey[i] - m);
      skey[i] = e;
      ssum += e;
    }
    ssum = wave_sum(ssum);
    const float inv = 1.0f / ssum;
    for (int i = lane; i < nksel; i += 64) skey[i] *= inv;
  } else if (wave == 1) {
    float m = NEGF;
    for (int i = nksel + lane; i < ntot; i += 64) m = fmaxf(m, skey[i]);
    m = wave_max(m);
    float ssum = 0.f;
    for (int i = nksel + lane; i < ntot; i += 64) {
      const float e = __expf(skey[i] - m);
      skey[i] = e;
      ssum += e;
    }
    ssum = wave_sum(ssum);
    const float inv = 1.0f / ssum;
    for (int i = nksel + lane; i < ntot; i += 64) skey[i] *= inv;
  }
  __syncthreads();

  // ---- phase 7: PV — all 8 waves, strided over keys; float2 of d per lane --
  {
    float2 as = {0.f, 0.f}, aw = {0.f, 0.f};
    const float* vb = v + h * DIM + 2 * lane;
    for (int i = wave; i < ntot; i += NW) {
      const float p = skey[i];
      if (i < nksel) {
        if (p != 0.f) {
          const int tp = blist[i >> 6] * SSZ + (i & 63);
          const float2 r = *(const float2*)(vb + tp * NH * DIM);
          as.x += p * r.x; as.y += p * r.y;
        }
      } else {
        const int tp = w0 + (i - nksel);
        const float2 r = *(const float2*)(vb + tp * NH * DIM);
        aw.x += p * r.x; aw.y += p * r.y;
      }
    }
    part_sel[wave][2 * lane] = as.x; part_sel[wave][2 * lane + 1] = as.y;
    part_win[wave][2 * lane] = aw.x; part_win[wave][2 * lane + 1] = aw.y;
  }
  __syncthreads();

  // ---- phase 8: cross-wave reduce + gated combine ----
  if (tid < DIM) {
    float oc = 0.f, os = 0.f, ow = 0.f;
#pragma unroll
    for (int w = 0; w < NW; ++w) {
      oc += part_cmp[w][tid];
      os += part_sel[w][tid];
      ow += part_win[w][tid];
    }
    out[(t * NH + h) * DIM + tid] =
        oc * gates[0] + os * gates[1] + ow * gates[2];
  }
}

extern "C" void kernel_launch(void* const* d_in, const int* in_sizes, int n_in,
                              void* d_out, int out_size, void* d_ws, size_t ws_size,
                              hipStream_t stream) {
  const float* q  = (const float*)d_in[0];
  const float* k  = (const float*)d_in[1];
  const float* v  = (const float*)d_in[2];
  const float* wg = (const float*)d_in[3];
  const float* bg = (const float*)d_in[4];
  float* out = (float*)d_out;

  float* cmpk = (float*)d_ws;
  float* cmpv = cmpk + NH * NCMP * DIM;

  nsa_compress<<<NCMP * NH, 128, 0, stream>>>(k, v, cmpk, cmpv);
  nsa_main<<<NH * S_LEN, NT, 0, stream>>>(q, k, v, wg, bg, cmpk, cmpv, out);
}

// Round 3
// 241.989 us; speedup vs baseline: 34.2386x; 28.9618x over previous
//
#include <hip/hip_runtime.h>

#define S_LEN 2048
#define NH 16
#define DIM 128
#define KSZ 32
#define STRD 16
#define SSZ 64
#define NSELB 32
#define NCMP 127
#define TOPN 16
#define WINSZ 512
#define NEGF (-1e30f)
#define NEGTH (-1e29f)
#define SCALE 0.088388347648318447f

typedef __attribute__((ext_vector_type(8))) short bf16x8;
typedef __attribute__((ext_vector_type(4))) float f32x4;

__device__ __forceinline__ unsigned short f2bf(float f) {
  unsigned u = __builtin_bit_cast(unsigned, f);
  return (unsigned short)((u + 0x7FFFu + ((u >> 16) & 1u)) >> 16);
}
__device__ __forceinline__ bf16x8 pack8(const float* f) {
  bf16x8 r;
#pragma unroll
  for (int i = 0; i < 8; ++i) r[i] = (short)f2bf(f[i]);
  return r;
}

// ---------- kernel 1: V^T global build: vtg[h][d][t] bf16 ----------
__global__ __launch_bounds__(256) void vt_build(const float* __restrict__ v,
                                                unsigned short* __restrict__ vtg) {
  const int c = blockIdx.x * 256 + threadIdx.x;   // 524288 chunks
  const int h = c >> 15;
  const int rem = c & 32767;
  const int d = rem >> 8;
  const int tc = rem & 255;                        // 8 t's per chunk
  float f[8];
#pragma unroll
  for (int i = 0; i < 8; ++i) f[i] = v[((tc * 8 + i) * NH + h) * DIM + d];
  bf16x8 r = pack8(f);
  *(bf16x8*)(vtg + ((h * DIM + d) * S_LEN + tc * 8)) = r;
}

// ---------- kernel 2: compress + bf16 outputs (cmpkb[h][c][d], cmpvt[h][d][c]) ----------
__global__ __launch_bounds__(128) void nsa_compress(
    const float* __restrict__ k, const float* __restrict__ v,
    unsigned short* __restrict__ cmpkb, unsigned short* __restrict__ cmpvt) {
  const int c = blockIdx.x & 127;
  const int h = blockIdx.x >> 7;
  const int d = threadIdx.x;
  float sk = 0.f, sv = 0.f;
  if (c < NCMP) {
    const int base = ((c * STRD) * NH + h) * DIM + d;
#pragma unroll
    for (int i = 0; i < KSZ; ++i) {
      sk += k[base + i * NH * DIM];
      sv += v[base + i * NH * DIM];
    }
    sk *= (1.0f / KSZ); sv *= (1.0f / KSZ);
  }
  cmpkb[(h * 128 + c) * 128 + d] = (c < NCMP) ? f2bf(sk) : 0;
  cmpvt[(h * 128 + d) * 128 + c] = (c < NCMP) ? f2bf(sv) : 0;
}

// ---------- kernel 3: main fused NSA ----------
// block = (h, 64-query tile); 256 threads = 4 waves; wave w owns queries t0+w*16..+15
__global__ __launch_bounds__(256, 2) void nsa_main(
    const float* __restrict__ q, const float* __restrict__ k,
    const float* __restrict__ v, const float* __restrict__ wg,
    const float* __restrict__ bg, const unsigned short* __restrict__ vtg,
    const unsigned short* __restrict__ cmpkb, const unsigned short* __restrict__ cmpvt,
    float* __restrict__ out) {
  __shared__ __align__(16) char klds[32 * 256];        // [32 keys][128 d] bf16, XOR swizzle
  __shared__ __align__(16) char vt[128 * 80];          // [128 d][32 keys] bf16, row stride 80B
  __shared__ __align__(16) float sc[4 * 16 * 132];     // per-wave [16 q][128+pad] f32
  __shared__ __align__(16) char pa[4 * 2048];          // per-wave [16 q][128B] P bf16 / ssel alias
  __shared__ unsigned maskLds[64];
  __shared__ unsigned unionLds;
  __shared__ float gatesLds[192];

  const int h = blockIdx.x >> 5;
  const int t0 = (blockIdx.x & 31) * 64;
  const int tid = threadIdx.x;
  const int lane = tid & 63;
  const int w = tid >> 6;
  const int l15 = lane & 15;
  const int l4 = lane >> 4;

  float* scw = sc + w * 16 * 132;
  char* paw = pa + w * 2048;

  if (tid < 64) maskLds[tid] = 0u;
  if (tid == 64) unionLds = 0u;

  // ---- gates (fp32, exact) ----
  {
    const int qloc = tid >> 2, g = tid & 3;
    if (g < 3) {
      const int tq = t0 + qloc;
      const float* qr = q + (tq * NH + h) * DIM;
      float acc = bg[g];
#pragma unroll
      for (int d4 = 0; d4 < DIM; d4 += 4) {
        const float4 qv = *(const float4*)(qr + d4);
        acc += qv.x * wg[(d4 + 0) * 3 + g] + qv.y * wg[(d4 + 1) * 3 + g] +
               qv.z * wg[(d4 + 2) * 3 + g] + qv.w * wg[(d4 + 3) * 3 + g];
      }
      gatesLds[qloc * 3 + g] = 1.0f / (1.0f + __expf(-acc));
    }
  }

  // ---- Q fragments (once): qf[ks], ks=0..3, row = l15, d = ks*32 + l4*8 + i ----
  bf16x8 qf[4];
  {
    const float* qp = q + ((t0 + w * 16 + l15) * NH + h) * DIM + l4 * 8;
#pragma unroll
    for (int ks = 0; ks < 4; ++ks) {
      float f[8];
#pragma unroll
      for (int i = 0; i < 4; ++i) f[i] = qp[ks * 32 + i];
#pragma unroll
      for (int i = 0; i < 4; ++i) f[4 + i] = qp[ks * 32 + 4 + i];
      qf[ks] = pack8(f);
    }
  }

  // ================= compressed branch: Pass A (QK -> sc) =================
  for (int ct = 0; ct < 4; ++ct) {
    __syncthreads();
    // stage cmpkb tile -> klds (bf16 copy, swizzled)
#pragma unroll
    for (int c = 0; c < 2; ++c) {
      const int e = tid + c * 256;
      const int key = e >> 4, dc = e & 15;
      *(bf16x8*)(klds + key * 256 + ((dc * 16) ^ ((key & 7) << 4))) =
          *(const bf16x8*)(cmpkb + (h * 128 + ct * 32 + key) * 128 + dc * 8);
    }
    __syncthreads();
    f32x4 s0 = {0, 0, 0, 0}, s1 = {0, 0, 0, 0};
#pragma unroll
    for (int ks = 0; ks < 4; ++ks) {
      const int db = ks * 64 + l4 * 16;
      bf16x8 b0 = *(const bf16x8*)(klds + l15 * 256 + (db ^ ((l15 & 7) << 4)));
      bf16x8 b1 = *(const bf16x8*)(klds + (16 + l15) * 256 + (db ^ (((16 + l15) & 7) << 4)));
      s0 = __builtin_amdgcn_mfma_f32_16x16x32_bf16(qf[ks], b0, s0, 0, 0, 0);
      s1 = __builtin_amdgcn_mfma_f32_16x16x32_bf16(qf[ks], b1, s1, 0, 0, 0);
    }
#pragma unroll
    for (int j = 0; j < 4; ++j) {
      const int qr = l4 * 4 + j;
      scw[qr * 132 + ct * 32 + l15] = s0[j] * SCALE;
      scw[qr * 132 + ct * 32 + 16 + l15] = s1[j] * SCALE;
    }
  }
  __syncthreads();

  // ---- exact softmax over 127 cmp scores (per wave; 4 lanes per query) ----
  {
    const int qq = lane >> 2, qg = lane & 3;
    const int tq = t0 + w * 16 + qq;
    const int nv = (tq >= KSZ - 1) ? ((tq - (KSZ - 1)) / STRD + 1) : 0;
    float x[32];
#pragma unroll
    for (int i = 0; i < 32; ++i) x[i] = scw[qq * 132 + qg * 32 + i];
    float m = NEGF;
#pragma unroll
    for (int i = 0; i < 32; ++i) {
      const int c = qg * 32 + i;
      if (c < nv) m = fmaxf(m, x[i]);
    }
    m = fmaxf(m, __shfl_xor(m, 1));
    m = fmaxf(m, __shfl_xor(m, 2));
    float s = 0.f;
#pragma unroll
    for (int i = 0; i < 32; ++i) {
      const int c = qg * 32 + i;
      x[i] = (c < nv) ? __expf(x[i] - m) : 0.f;
      s += x[i];
    }
    s += __shfl_xor(s, 1);
    s += __shfl_xor(s, 2);
    const float inv = (nv > 0) ? (1.0f / s) : 0.f;
#pragma unroll
    for (int i = 0; i < 32; ++i) scw[qq * 132 + qg * 32 + i] = x[i] * inv;
  }
  __syncthreads();

  // ---- selection scores + top-16 (exact tie semantics) ----
  {
    const int qq = lane >> 2, jg = lane & 3;
    const int tq = t0 + w * 16 + qq;
    float* ss = (float*)paw;
    float vj[8];
#pragma unroll
    for (int i = 0; i < 8; ++i) {
      const int j = jg * 8 + i;
      const int lo = (4 * j - 1 > 0) ? 4 * j - 1 : 0;
      const int hi = (4 * j + 3 < NCMP - 1) ? 4 * j + 3 : NCMP - 1;
      float ps = 0.f;
      for (int c = lo; c <= hi; ++c) ps += scw[qq * 132 + c];
      float val = (j * SSZ <= tq) ? ps : -1.0f;
      if (j == (tq >> 6)) val += 1e6f;
      vj[i] = val;
      ss[qq * 32 + j] = val;
    }
    __syncthreads();
#pragma unroll
    for (int i = 0; i < 8; ++i) {
      const int j = jg * 8 + i;
      const float my = vj[i];
      int rank = 0;
      for (int jp = 0; jp < NSELB; ++jp) {
        const float o = ss[qq * 32 + jp];
        rank += (o > my) || (o == my && jp < j);
      }
      if (rank < TOPN && (j * SSZ <= tq)) {
        atomicOr(&maskLds[w * 16 + qq], 1u << j);
        atomicOr(&unionLds, 1u << j);
      }
    }
  }
  __syncthreads();

  unsigned maskq[4];
#pragma unroll
  for (int j = 0; j < 4; ++j) maskq[j] = maskLds[w * 16 + l4 * 4 + j];
  const unsigned unionMask = unionLds;

  // ================= compressed branch: Pass B (PV) =================
  f32x4 accA[8], accB[8];
#pragma unroll
  for (int n = 0; n < 8; ++n) accA[n] = (f32x4){0, 0, 0, 0};
  for (int ct = 0; ct < 4; ++ct) {
    __syncthreads();
#pragma unroll
    for (int c = 0; c < 2; ++c) {
      const int e = tid + c * 256;
      const int d = e >> 2, kc = e & 3;
      *(bf16x8*)(vt + d * 80 + kc * 16) =
          *(const bf16x8*)(cmpvt + (h * 128 + d) * 128 + ct * 32 + kc * 8);
    }
    __syncthreads();
    // A-frag: P rows from sc (fp32 -> bf16)
    float f[8];
#pragma unroll
    for (int i = 0; i < 8; ++i) f[i] = scw[l15 * 132 + ct * 32 + l4 * 8 + i];
    bf16x8 ap = pack8(f);
#pragma unroll
    for (int n = 0; n < 8; ++n) {
      bf16x8 bv = *(const bf16x8*)(vt + (n * 16 + l15) * 80 + l4 * 16);
      accA[n] = __builtin_amdgcn_mfma_f32_16x16x32_bf16(ap, bv, accA[n], 0, 0, 0);
    }
  }
  __syncthreads();
  // dump g0 * Ocmp into sc (probs no longer needed)
#pragma unroll
  for (int j = 0; j < 4; ++j) {
    const int qr = l4 * 4 + j;
    const float g0 = gatesLds[(w * 16 + qr) * 3 + 0];
#pragma unroll
    for (int n = 0; n < 8; ++n) scw[qr * 132 + n * 16 + l15] = g0 * accA[n][j];
  }

  // ================= main pass: selected + window =================
  float mS[4], lS[4], mW[4], lW[4];
#pragma unroll
  for (int j = 0; j < 4; ++j) { mS[j] = NEGF; lS[j] = 0.f; mW[j] = NEGF; lW[j] = 0.f; }
#pragma unroll
  for (int n = 0; n < 8; ++n) { accA[n] = (f32x4){0, 0, 0, 0}; accB[n] = (f32x4){0, 0, 0, 0}; }

  const int ktmax = (t0 + 63) >> 5;
  for (int kt = 0; kt <= ktmax; ++kt) {
    const int kt0 = kt * 32;
    const int jb = kt >> 1;
    const bool selAny = (unionMask >> jb) & 1u;
    const bool winAny = (kt0 + 31) >= (t0 - WINSZ);
    if (!selAny && !winAny) continue;
    __syncthreads();
    // stage K tile (fp32 -> bf16, swizzled)
#pragma unroll
    for (int c = 0; c < 2; ++c) {
      const int e = tid + c * 256;
      const int key = e >> 4, dc = e & 15;
      const float* src = k + ((kt0 + key) * NH + h) * DIM + dc * 8;
      float f[8];
#pragma unroll
      for (int i = 0; i < 8; ++i) f[i] = src[i];
      *(bf16x8*)(klds + key * 256 + ((dc * 16) ^ ((key & 7) << 4))) = pack8(f);
    }
    // stage V tile from vtg
#pragma unroll
    for (int c = 0; c < 2; ++c) {
      const int e = tid + c * 256;
      const int d = e >> 2, kc = e & 3;
      *(bf16x8*)(vt + d * 80 + kc * 16) =
          *(const bf16x8*)(vtg + (h * 128 + d) * S_LEN + kt0 + kc * 8);
    }
    __syncthreads();

    // shared QK
    f32x4 s0 = {0, 0, 0, 0}, s1 = {0, 0, 0, 0};
#pragma unroll
    for (int ks = 0; ks < 4; ++ks) {
      const int db = ks * 64 + l4 * 16;
      bf16x8 b0 = *(const bf16x8*)(klds + l15 * 256 + (db ^ ((l15 & 7) << 4)));
      bf16x8 b1 = *(const bf16x8*)(klds + (16 + l15) * 256 + (db ^ (((16 + l15) & 7) << 4)));
      s0 = __builtin_amdgcn_mfma_f32_16x16x32_bf16(qf[ks], b0, s0, 0, 0, 0);
      s1 = __builtin_amdgcn_mfma_f32_16x16x32_bf16(qf[ks], b1, s1, 0, 0, 0);
    }
#pragma unroll
    for (int j = 0; j < 4; ++j) { s0[j] *= SCALE; s1[j] *= SCALE; }
    const int c0 = kt0 + l15, c1 = kt0 + 16 + l15;

    // ---- selected branch ----
    if (selAny) {
#pragma unroll
      for (int j = 0; j < 4; ++j) {
        const int qr = l4 * 4 + j;
        const int tq = t0 + w * 16 + qr;
        const bool mb = (maskq[j] >> jb) & 1u;
        const float v0 = (mb && c0 <= tq) ? s0[j] : NEGF;
        const float v1 = (mb && c1 <= tq) ? s1[j] : NEGF;
        float rm = fmaxf(v0, v1);
        rm = fmaxf(rm, __shfl_xor(rm, 1));
        rm = fmaxf(rm, __shfl_xor(rm, 2));
        rm = fmaxf(rm, __shfl_xor(rm, 4));
        rm = fmaxf(rm, __shfl_xor(rm, 8));
        const float mn = fmaxf(mS[j], rm);
        const float sf = __expf(mS[j] - mn);
        const float p0 = (v0 > NEGTH) ? __expf(v0 - mn) : 0.f;
        const float p1 = (v1 > NEGTH) ? __expf(v1 - mn) : 0.f;
        float rs = p0 + p1;
        rs += __shfl_xor(rs, 1);
        rs += __shfl_xor(rs, 2);
        rs += __shfl_xor(rs, 4);
        rs += __shfl_xor(rs, 8);
        lS[j] = lS[j] * sf + rs;
        mS[j] = mn;
#pragma unroll
        for (int n = 0; n < 8; ++n) accA[n][j] *= sf;
        *(unsigned short*)(paw + qr * 128 + ((l15 * 2) ^ ((qr & 7) << 4))) = f2bf(p0);
        *(unsigned short*)(paw + qr * 128 + (((16 + l15) * 2) ^ ((qr & 7) << 4))) = f2bf(p1);
      }
      bf16x8 ap = *(const bf16x8*)(paw + l15 * 128 + ((l4 * 16) ^ ((l15 & 7) << 4)));
#pragma unroll
      for (int n = 0; n < 8; ++n) {
        bf16x8 bv = *(const bf16x8*)(vt + (n * 16 + l15) * 80 + l4 * 16);
        accA[n] = __builtin_amdgcn_mfma_f32_16x16x32_bf16(ap, bv, accA[n], 0, 0, 0);
      }
    }
    // ---- window branch ----
    if (winAny) {
#pragma unroll
      for (int j = 0; j < 4; ++j) {
        const int qr = l4 * 4 + j;
        const int tq = t0 + w * 16 + qr;
        const float v0 = (c0 <= tq && c0 >= tq - WINSZ) ? s0[j] : NEGF;
        const float v1 = (c1 <= tq && c1 >= tq - WINSZ) ? s1[j] : NEGF;
        float rm = fmaxf(v0, v1);
        rm = fmaxf(rm, __shfl_xor(rm, 1));
        rm = fmaxf(rm, __shfl_xor(rm, 2));
        rm = fmaxf(rm, __shfl_xor(rm, 4));
        rm = fmaxf(rm, __shfl_xor(rm, 8));
        const float mn = fmaxf(mW[j], rm);
        const float sf = __expf(mW[j] - mn);
        const float p0 = (v0 > NEGTH) ? __expf(v0 - mn) : 0.f;
        const float p1 = (v1 > NEGTH) ? __expf(v1 - mn) : 0.f;
        float rs = p0 + p1;
        rs += __shfl_xor(rs, 1);
        rs += __shfl_xor(rs, 2);
        rs += __shfl_xor(rs, 4);
        rs += __shfl_xor(rs, 8);
        lW[j] = lW[j] * sf + rs;
        mW[j] = mn;
#pragma unroll
        for (int n = 0; n < 8; ++n) accB[n][j] *= sf;
        *(unsigned short*)(paw + qr * 128 + ((l15 * 2) ^ ((qr & 7) << 4))) = f2bf(p0);
        *(unsigned short*)(paw + qr * 128 + (((16 + l15) * 2) ^ ((qr & 7) << 4))) = f2bf(p1);
      }
      bf16x8 ap = *(const bf16x8*)(paw + l15 * 128 + ((l4 * 16) ^ ((l15 & 7) << 4)));
#pragma unroll
      for (int n = 0; n < 8; ++n) {
        bf16x8 bv = *(const bf16x8*)(vt + (n * 16 + l15) * 80 + l4 * 16);
        accB[n] = __builtin_amdgcn_mfma_f32_16x16x32_bf16(ap, bv, accB[n], 0, 0, 0);
      }
    }
  }

  // ---- epilogue: combine ----
#pragma unroll
  for (int j = 0; j < 4; ++j) {
    const int qr = l4 * 4 + j;
    const int tq = t0 + w * 16 + qr;
    const float g1 = gatesLds[(w * 16 + qr) * 3 + 1];
    const float g2 = gatesLds[(w * 16 + qr) * 3 + 2];
    const float rlS = 1.0f / lS[j];
    const float rlW = 1.0f / lW[j];
#pragma unroll
    for (int n = 0; n < 8; ++n) {
      const float val = scw[qr * 132 + n * 16 + l15] + g1 * accA[n][j] * rlS +
                        g2 * accB[n][j] * rlW;
      out[(tq * NH + h) * DIM + n * 16 + l15] = val;
    }
  }
}

extern "C" void kernel_launch(void* const* d_in, const int* in_sizes, int n_in,
                              void* d_out, int out_size, void* d_ws, size_t ws_size,
                              hipStream_t stream) {
  const float* q  = (const float*)d_in[0];
  const float* k  = (const float*)d_in[1];
  const float* v  = (const float*)d_in[2];
  const float* wg = (const float*)d_in[3];
  const float* bg = (const float*)d_in[4];
  float* out = (float*)d_out;

  unsigned short* vtg   = (unsigned short*)d_ws;                    // 8 MB
  unsigned short* cmpkb = vtg + NH * DIM * S_LEN;                   // 512 KB
  unsigned short* cmpvt = cmpkb + NH * 128 * 128;                   // 512 KB

  vt_build<<<2048, 256, 0, stream>>>(v, vtg);
  nsa_compress<<<NH * 128, 128, 0, stream>>>(k, v, cmpkb, cmpvt);
  nsa_main<<<NH * 32, 256, 0, stream>>>(q, k, v, wg, bg, vtg, cmpkb, cmpvt, out);
}